// Round 1
// baseline (2051.963 us; speedup 1.0000x reference)
//
#include <hip/hip_runtime.h>
#include <math.h>

#define T_DIM 4096
#define H_DIM 2048
#define N_DIM 1024
#define CHUNK 64
#define NCHUNK (T_DIM / CHUNK)

// ---------------------------------------------------------------------------
// Kernel 1: Bu = inputs @ (B * gamma)^T   (re and im in one pass)
// A = inputs [T,H] row-major, B = B_re/B_im [N,H] row-major (both K-contig).
// 64x64 output tile, 256 threads, 4x4 microtile. gamma applied in epilogue.
// ---------------------------------------------------------------------------
__global__ __launch_bounds__(256) void bu_gemm(
    const float* __restrict__ U, const float* __restrict__ Bre,
    const float* __restrict__ Bim, const float* __restrict__ glog,
    float* __restrict__ BuRe, float* __restrict__ BuIm)
{
    __shared__ float As[64][17];
    __shared__ float BsR[64][17];
    __shared__ float BsI[64][17];

    const int tid = threadIdx.x;
    const int tx = tid & 15, ty = tid >> 4;
    const int row0 = blockIdx.y * 64;   // T
    const int col0 = blockIdx.x * 64;   // N

    float accR[4][4] = {{0.f}}, accI[4][4] = {{0.f}};

    for (int k0 = 0; k0 < H_DIM; k0 += 16) {
#pragma unroll
        for (int i = 0; i < 4; ++i) {
            int e = tid + i * 256;
            int r = e >> 4, c = e & 15;
            As[r][c]  = U[(size_t)(row0 + r) * H_DIM + k0 + c];
            BsR[r][c] = Bre[(size_t)(col0 + r) * H_DIM + k0 + c];
            BsI[r][c] = Bim[(size_t)(col0 + r) * H_DIM + k0 + c];
        }
        __syncthreads();
#pragma unroll
        for (int kk = 0; kk < 16; ++kk) {
            float a[4], br[4], bi[4];
#pragma unroll
            for (int i = 0; i < 4; ++i) a[i] = As[ty * 4 + i][kk];
#pragma unroll
            for (int j = 0; j < 4; ++j) { br[j] = BsR[tx * 4 + j][kk]; bi[j] = BsI[tx * 4 + j][kk]; }
#pragma unroll
            for (int i = 0; i < 4; ++i)
#pragma unroll
                for (int j = 0; j < 4; ++j) {
                    accR[i][j] += a[i] * br[j];
                    accI[i][j] += a[i] * bi[j];
                }
        }
        __syncthreads();
    }

    // epilogue: scale by gamma[n] = exp(gamma_log[n]) and store
#pragma unroll
    for (int j = 0; j < 4; ++j) {
        int n = col0 + tx * 4 + j;
        float g = expf(glog[n]);
#pragma unroll
        for (int i = 0; i < 4; ++i) {
            size_t p = (size_t)(row0 + ty * 4 + i) * N_DIM + n;
            BuRe[p] = accR[i][j] * g;
            BuIm[p] = accI[i][j] * g;
        }
    }
}

// ---------------------------------------------------------------------------
// Kernel 2a: local inclusive scans within chunks of CHUNK timesteps (in place)
// one thread per (chunk, channel); consecutive threads -> consecutive channels
// ---------------------------------------------------------------------------
__global__ __launch_bounds__(256) void scan_local(
    float* __restrict__ BuRe, float* __restrict__ BuIm,
    const float* __restrict__ nu, const float* __restrict__ theta,
    float* __restrict__ carR, float* __restrict__ carI)
{
    int idx = blockIdx.x * 256 + threadIdx.x;      // 0 .. NCHUNK*N-1
    int chan = idx & (N_DIM - 1);
    int chunk = idx >> 10;

    float a = expf(nu[chan]);
    float b = expf(theta[chan]);
    float m = expf(-a);
    float s, c;
    __sincosf(b, &s, &c);
    float lr = m * c, li = m * s;

    float hr = 0.f, hi = 0.f;
    size_t base = (size_t)chunk * CHUNK * N_DIM + chan;
    for (int i = 0; i < CHUNK; ++i) {
        size_t p = base + (size_t)i * N_DIM;
        float br = BuRe[p], bi = BuIm[p];
        float nr = lr * hr - li * hi + br;
        float ni = lr * hi + li * hr + bi;
        hr = nr; hi = ni;
        BuRe[p] = hr; BuIm[p] = hi;
    }
    carR[(size_t)chunk * N_DIM + chan] = hr;
    carI[(size_t)chunk * N_DIM + chan] = hi;
}

// ---------------------------------------------------------------------------
// Kernel 2b: sequential scan over the NCHUNK chunk carries, per channel
// carry_c = lambda^CHUNK * carry_{c-1} + carry_c  (in place)
// ---------------------------------------------------------------------------
__global__ __launch_bounds__(256) void scan_carry(
    float* __restrict__ carR, float* __restrict__ carI,
    const float* __restrict__ nu, const float* __restrict__ theta)
{
    int chan = blockIdx.x * 256 + threadIdx.x;     // 0 .. N-1
    float a = expf(nu[chan]);
    float b = expf(theta[chan]);
    // lambda^CHUNK = exp(-CHUNK*a + i*CHUNK*b), computed in closed form
    float m = expf(-(float)CHUNK * a);
    float s, c;
    __sincosf((float)CHUNK * b, &s, &c);
    float lr = m * c, li = m * s;

    float hr = carR[chan], hi = carI[chan];
    for (int ck = 1; ck < NCHUNK; ++ck) {
        size_t p = (size_t)ck * N_DIM + chan;
        float nr = lr * hr - li * hi + carR[p];
        float ni = lr * hi + li * hr + carI[p];
        hr = nr; hi = ni;
        carR[p] = hr; carI[p] = hi;
    }
}

// ---------------------------------------------------------------------------
// Kernel 2c: fixup  h[t] = lambda^{(t%CHUNK)+1} * carry[chunk-1] + local[t]
// lambda^p computed in closed form (exact, no error accumulation)
// ---------------------------------------------------------------------------
__global__ __launch_bounds__(256) void scan_fixup(
    float* __restrict__ BuRe, float* __restrict__ BuIm,
    const float* __restrict__ carR, const float* __restrict__ carI,
    const float* __restrict__ nu, const float* __restrict__ theta)
{
    size_t idx = (size_t)blockIdx.x * 256 + threadIdx.x;   // 0 .. T*N-1
    int chan = (int)(idx & (N_DIM - 1));
    size_t t = idx >> 10;
    int chunk = (int)(t >> 6);            // t / CHUNK
    if (chunk == 0) return;
    float pf = (float)((t & (CHUNK - 1)) + 1);

    float a = expf(nu[chan]);
    float b = expf(theta[chan]);
    float m = expf(-pf * a);
    float s, c;
    __sincosf(pf * b, &s, &c);
    float lr = m * c, li = m * s;

    size_t cp = (size_t)(chunk - 1) * N_DIM + chan;
    float cr = carR[cp], ci = carI[cp];
    BuRe[idx] += lr * cr - li * ci;
    BuIm[idx] += lr * ci + li * cr;
}

// ---------------------------------------------------------------------------
// Kernel 3: y = h_re @ C_re^T - h_im @ C_im^T + D * u
// h [T,N] row-major, C [H,N] row-major (both K-contig). Same tiling as k1.
// ---------------------------------------------------------------------------
__global__ __launch_bounds__(256) void out_gemm(
    const float* __restrict__ HRe, const float* __restrict__ HIm,
    const float* __restrict__ Cre, const float* __restrict__ Cim,
    const float* __restrict__ D, const float* __restrict__ U,
    float* __restrict__ Y)
{
    __shared__ float Ar[64][17];
    __shared__ float Ai[64][17];
    __shared__ float Br[64][17];
    __shared__ float Bi[64][17];

    const int tid = threadIdx.x;
    const int tx = tid & 15, ty = tid >> 4;
    const int row0 = blockIdx.y * 64;   // T
    const int col0 = blockIdx.x * 64;   // H

    float acc[4][4] = {{0.f}};

    for (int k0 = 0; k0 < N_DIM; k0 += 16) {
#pragma unroll
        for (int i = 0; i < 4; ++i) {
            int e = tid + i * 256;
            int r = e >> 4, c = e & 15;
            Ar[r][c] = HRe[(size_t)(row0 + r) * N_DIM + k0 + c];
            Ai[r][c] = HIm[(size_t)(row0 + r) * N_DIM + k0 + c];
            Br[r][c] = Cre[(size_t)(col0 + r) * N_DIM + k0 + c];
            Bi[r][c] = Cim[(size_t)(col0 + r) * N_DIM + k0 + c];
        }
        __syncthreads();
#pragma unroll
        for (int kk = 0; kk < 16; ++kk) {
            float ar[4], ai[4], br[4], bi[4];
#pragma unroll
            for (int i = 0; i < 4; ++i) { ar[i] = Ar[ty * 4 + i][kk]; ai[i] = Ai[ty * 4 + i][kk]; }
#pragma unroll
            for (int j = 0; j < 4; ++j) { br[j] = Br[tx * 4 + j][kk]; bi[j] = Bi[tx * 4 + j][kk]; }
#pragma unroll
            for (int i = 0; i < 4; ++i)
#pragma unroll
                for (int j = 0; j < 4; ++j)
                    acc[i][j] += ar[i] * br[j] - ai[i] * bi[j];
        }
        __syncthreads();
    }

#pragma unroll
    for (int i = 0; i < 4; ++i) {
        int t = row0 + ty * 4 + i;
#pragma unroll
        for (int j = 0; j < 4; ++j) {
            int h = col0 + tx * 4 + j;
            size_t p = (size_t)t * H_DIM + h;
            Y[p] = acc[i][j] + D[h] * U[p];
        }
    }
}

extern "C" void kernel_launch(void* const* d_in, const int* in_sizes, int n_in,
                              void* d_out, int out_size, void* d_ws, size_t ws_size,
                              hipStream_t stream)
{
    const float* U     = (const float*)d_in[0];   // [T,H]
    const float* nu    = (const float*)d_in[1];   // [N]
    const float* theta = (const float*)d_in[2];   // [N]
    const float* glog  = (const float*)d_in[3];   // [N]
    const float* Bre   = (const float*)d_in[4];   // [N,H]
    const float* Bim   = (const float*)d_in[5];   // [N,H]
    const float* Cre   = (const float*)d_in[6];   // [H,N]
    const float* Cim   = (const float*)d_in[7];   // [H,N]
    const float* D     = (const float*)d_in[8];   // [H]
    float* Y = (float*)d_out;

    float* BuRe = (float*)d_ws;
    float* BuIm = BuRe + (size_t)T_DIM * N_DIM;
    float* carR = BuIm + (size_t)T_DIM * N_DIM;
    float* carI = carR + (size_t)NCHUNK * N_DIM;

    bu_gemm<<<dim3(N_DIM / 64, T_DIM / 64), 256, 0, stream>>>(U, Bre, Bim, glog, BuRe, BuIm);
    scan_local<<<(NCHUNK * N_DIM) / 256, 256, 0, stream>>>(BuRe, BuIm, nu, theta, carR, carI);
    scan_carry<<<N_DIM / 256, 256, 0, stream>>>(carR, carI, nu, theta);
    scan_fixup<<<(T_DIM * (size_t)N_DIM) / 256, 256, 0, stream>>>(BuRe, BuIm, carR, carI, nu, theta);
    out_gemm<<<dim3(H_DIM / 64, T_DIM / 64), 256, 0, stream>>>(BuRe, BuIm, Cre, Cim, D, U, Y);
}

// Round 2
// 158.062 us; speedup vs baseline: 12.9820x; 12.9820x over previous
//
#include <hip/hip_runtime.h>
#include <math.h>

#define T_DIM 4096
#define H_DIM 2048
#define N_DIM 1024
#define N2    2048           // 2*N (concat re/im)
#define KK    2048           // K of both GEMMs
#define CHUNK 64
#define NCHUNK (T_DIM / CHUNK)

using u16   = unsigned short;
using u16x4 = __attribute__((ext_vector_type(4))) u16;
using bf16x8 = __attribute__((ext_vector_type(8))) short;
using f32x4  = __attribute__((ext_vector_type(4))) float;

typedef const __attribute__((address_space(1))) u16 glob_u16;
typedef __attribute__((address_space(3))) u16 lds_u16;

__device__ inline void gload16(const u16* g, u16* l) {
    // async global->LDS, 16B per lane; LDS dest = wave-uniform base + lane*16
    __builtin_amdgcn_global_load_lds((glob_u16*)g, (lds_u16*)l, 16, 0, 0);
}

__device__ inline u16 f2bf(float x) {   // RNE fp32->bf16
    unsigned u = __builtin_bit_cast(unsigned, x);
    u += 0x7fffu + ((u >> 16) & 1u);
    return (u16)(u >> 16);
}

// ---------------------------------------------------------------------------
// Conversion kernels (fold gamma into B, minus into C_im half)
// ---------------------------------------------------------------------------
__global__ __launch_bounds__(256) void cvt_u_k(const float* __restrict__ X,
                                               u16* __restrict__ Y) {
    size_t i = ((size_t)blockIdx.x * 256 + threadIdx.x) * 4;
    float4 v = *(const float4*)(X + i);
    u16x4 o = { f2bf(v.x), f2bf(v.y), f2bf(v.z), f2bf(v.w) };
    *(u16x4*)(Y + i) = o;
}

__global__ __launch_bounds__(256) void cvt_b_k(const float* __restrict__ Bre,
                                               const float* __restrict__ Bim,
                                               const float* __restrict__ glog,
                                               u16* __restrict__ Bcat) {
    size_t i = ((size_t)blockIdx.x * 256 + threadIdx.x) * 4;
    int n = (int)(i >> 11);          // row in [0, 2048)
    size_t h = i & 2047;
    int nn = n & (N_DIM - 1);
    float g = expf(glog[nn]);
    const float* src = (n < N_DIM ? Bre : Bim) + (size_t)nn * H_DIM + h;
    float4 v = *(const float4*)src;
    u16x4 o = { f2bf(v.x * g), f2bf(v.y * g), f2bf(v.z * g), f2bf(v.w * g) };
    *(u16x4*)(Bcat + i) = o;
}

__global__ __launch_bounds__(256) void cvt_c_k(const float* __restrict__ Cre,
                                               const float* __restrict__ Cim,
                                               u16* __restrict__ Ccat) {
    size_t i = ((size_t)blockIdx.x * 256 + threadIdx.x) * 4;
    int hrow = (int)(i >> 11);
    int n = (int)(i & 2047);
    float sgn = 1.f;
    const float* src;
    if (n < N_DIM) src = Cre + (size_t)hrow * N_DIM + n;
    else { src = Cim + (size_t)hrow * N_DIM + (n - N_DIM); sgn = -1.f; }
    float4 v = *(const float4*)src;
    u16x4 o = { f2bf(v.x * sgn), f2bf(v.y * sgn), f2bf(v.z * sgn), f2bf(v.w * sgn) };
    *(u16x4*)(Ccat + i) = o;
}

// ---------------------------------------------------------------------------
// bf16 NT GEMM, m97 structure: 128x128 tile, BK=32, 4 waves (2x2), each wave
// 64x64 via 4x4 frags of mfma_f32_16x16x32_bf16. global_load_lds width 16.
// A [4096][2048] bf16 row-major, B [2048][2048] bf16 row-major (N,K), C fp32.
// EPI=1: C += D[col]*U[row][col]
// ---------------------------------------------------------------------------
template <int EPI>
__global__ __launch_bounds__(256) void gemm_nt(const u16* __restrict__ A,
                                               const u16* __restrict__ B,
                                               float* __restrict__ C,
                                               const float* __restrict__ D,
                                               const float* __restrict__ U) {
    __shared__ u16 lds[8192];                 // A tile [0,4096), B tile [4096,8192)
    const int tid = threadIdx.x;
    const int wave = tid >> 6, lane = tid & 63;
    const int bm = blockIdx.x >> 4, bn = blockIdx.x & 15;   // 32 x 16 tiles
    const size_t row0 = (size_t)bm * 128, col0 = (size_t)bn * 128;
    const int rA = tid >> 2;                  // 0..63 (staging row)
    const int kcA = (tid & 3) * 8;            // staging k-offset (8 bf16 = 16B)
    const int wr = wave >> 1, wc = wave & 1;  // wave's 64x64 quadrant
    const int fr = lane & 15, fq = lane >> 4; // fragment row / k-group

    const u16* aSrc0 = A + (row0 + rA) * (size_t)KK + kcA;
    const u16* aSrc1 = aSrc0 + (size_t)64 * KK;
    const u16* bSrc0 = B + (col0 + rA) * (size_t)KK + kcA;
    const u16* bSrc1 = bSrc0 + (size_t)64 * KK;
    u16* ldsA0 = &lds[wave * 512];
    u16* ldsA1 = &lds[2048 + wave * 512];
    u16* ldsB0 = &lds[4096 + wave * 512];
    u16* ldsB1 = &lds[6144 + wave * 512];

    f32x4 acc[4][4] = {};

    for (int k0 = 0; k0 < KK; k0 += 32) {
        gload16(aSrc0 + k0, ldsA0);
        gload16(aSrc1 + k0, ldsA1);
        gload16(bSrc0 + k0, ldsB0);
        gload16(bSrc1 + k0, ldsB1);
        __syncthreads();                      // drains vmcnt -> LDS tiles ready
        bf16x8 af[4], bfv[4];
#pragma unroll
        for (int m = 0; m < 4; ++m)
            af[m] = *(const bf16x8*)&lds[(wr * 64 + m * 16 + fr) * 32 + fq * 8];
#pragma unroll
        for (int n = 0; n < 4; ++n)
            bfv[n] = *(const bf16x8*)&lds[4096 + (wc * 64 + n * 16 + fr) * 32 + fq * 8];
#pragma unroll
        for (int m = 0; m < 4; ++m)
#pragma unroll
            for (int n = 0; n < 4; ++n)
                acc[m][n] = __builtin_amdgcn_mfma_f32_16x16x32_bf16(
                    af[m], bfv[n], acc[m][n], 0, 0, 0);
        __syncthreads();                      // tiles consumed, safe to restage
    }

    // epilogue: C/D layout col=lane&15, row=(lane>>4)*4+reg  [m89/m91 verified]
    const int crow = (int)row0 + wr * 64 + fq * 4;
    const int ccol = (int)col0 + wc * 64 + fr;
#pragma unroll
    for (int m = 0; m < 4; ++m)
#pragma unroll
        for (int n = 0; n < 4; ++n) {
            int cc = ccol + n * 16;
#pragma unroll
            for (int j = 0; j < 4; ++j) {
                int r = crow + m * 16 + j;
                size_t p = (size_t)r * N2 + cc;
                float v = acc[m][n][j];
                if constexpr (EPI) v += D[cc] * U[p];
                C[p] = v;
            }
        }
}

// ---------------------------------------------------------------------------
// Scan over [T, 2N] layout: re at col c, im at col c+N.
// ---------------------------------------------------------------------------
__global__ __launch_bounds__(256) void scan_local_k(float* __restrict__ Bu,
                                                    const float* __restrict__ nu,
                                                    const float* __restrict__ theta,
                                                    float* __restrict__ car) {
    int idx = blockIdx.x * 256 + threadIdx.x;   // 0 .. NCHUNK*N-1
    int chan = idx & (N_DIM - 1);
    int chunk = idx >> 10;
    float a = expf(nu[chan]), b = expf(theta[chan]);
    float m = expf(-a), s, c;
    __sincosf(b, &s, &c);
    float lr = m * c, li = m * s;
    float hr = 0.f, hi = 0.f;
    size_t base = (size_t)chunk * CHUNK * N2 + chan;
    for (int i = 0; i < CHUNK; ++i) {
        size_t p = base + (size_t)i * N2;
        float br = Bu[p], bi = Bu[p + N_DIM];
        float nr = fmaf(lr, hr, fmaf(-li, hi, br));
        float ni = fmaf(lr, hi, fmaf(li, hr, bi));
        hr = nr; hi = ni;
        Bu[p] = hr; Bu[p + N_DIM] = hi;
    }
    car[(size_t)chunk * N2 + chan] = hr;
    car[(size_t)chunk * N2 + N_DIM + chan] = hi;
}

__global__ __launch_bounds__(256) void scan_carry_k(float* __restrict__ car,
                                                    const float* __restrict__ nu,
                                                    const float* __restrict__ theta) {
    __shared__ float sR[NCHUNK][65], sI[NCHUNK][65];
    int tid = threadIdx.x;
    int chan0 = blockIdx.x * 64;
    for (int i = tid; i < NCHUNK * 64; i += 256) {
        int ck = i >> 6, c = i & 63;
        sR[ck][c] = car[(size_t)ck * N2 + chan0 + c];
        sI[ck][c] = car[(size_t)ck * N2 + N_DIM + chan0 + c];
    }
    __syncthreads();
    if (tid < 64) {
        int chan = chan0 + tid;
        float a = expf(nu[chan]), b = expf(theta[chan]);
        float m = expf(-(float)CHUNK * a), s, c;   // lambda^CHUNK closed-form
        __sincosf((float)CHUNK * b, &s, &c);
        float lr = m * c, li = m * s;
        float hr = sR[0][tid], hi = sI[0][tid];
        for (int ck = 1; ck < NCHUNK; ++ck) {
            float nr = fmaf(lr, hr, fmaf(-li, hi, sR[ck][tid]));
            float ni = fmaf(lr, hi, fmaf(li, hr, sI[ck][tid]));
            hr = nr; hi = ni;
            sR[ck][tid] = hr; sI[ck][tid] = hi;
        }
    }
    __syncthreads();
    for (int i = tid; i < NCHUNK * 64; i += 256) {
        int ck = i >> 6, c = i & 63;
        car[(size_t)ck * N2 + chan0 + c] = sR[ck][c];
        car[(size_t)ck * N2 + N_DIM + chan0 + c] = sI[ck][c];
    }
}

// fixup h[t] = lambda^{(t%CHUNK)+1}*carry[chunk-1] + local[t], write bf16 h
__global__ __launch_bounds__(256) void fixup_cvt_k(const float* __restrict__ Bu,
                                                   const float* __restrict__ car,
                                                   const float* __restrict__ nu,
                                                   const float* __restrict__ theta,
                                                   u16* __restrict__ Hbf) {
    size_t idx = (size_t)blockIdx.x * 256 + threadIdx.x;  // 0 .. T*N-1
    int chan = (int)(idx & (N_DIM - 1));
    size_t t = idx >> 10;
    int chunk = (int)(t >> 6);
    size_t p = t * N2 + chan;
    float hr = Bu[p], hi = Bu[p + N_DIM];
    if (chunk > 0) {
        float pf = (float)((t & (CHUNK - 1)) + 1);
        float a = expf(nu[chan]), b = expf(theta[chan]);
        float m = expf(-pf * a), s, c;
        __sincosf(pf * b, &s, &c);
        float lr = m * c, li = m * s;
        size_t cp = (size_t)(chunk - 1) * N2 + chan;
        float cr = car[cp], ci = car[cp + N_DIM];
        hr += lr * cr - li * ci;
        hi += lr * ci + li * cr;
    }
    Hbf[p] = f2bf(hr);
    Hbf[p + N_DIM] = f2bf(hi);
}

extern "C" void kernel_launch(void* const* d_in, const int* in_sizes, int n_in,
                              void* d_out, int out_size, void* d_ws, size_t ws_size,
                              hipStream_t stream) {
    const float* U     = (const float*)d_in[0];   // [T,H]
    const float* nu    = (const float*)d_in[1];   // [N]
    const float* theta = (const float*)d_in[2];   // [N]
    const float* glog  = (const float*)d_in[3];   // [N]
    const float* Bre   = (const float*)d_in[4];   // [N,H]
    const float* Bim   = (const float*)d_in[5];   // [N,H]
    const float* Cre   = (const float*)d_in[6];   // [H,N]
    const float* Cim   = (const float*)d_in[7];   // [H,N]
    const float* Dp    = (const float*)d_in[8];   // [H]
    float* Y = (float*)d_out;

    // workspace layout (80.5 MB total)
    u16* Ubf  = (u16*)d_ws;                             // T*H      bf16 (16 MB)
    u16* Bcat = Ubf + (size_t)T_DIM * H_DIM;            // 2N*H     bf16 ( 8 MB)
    u16* Ccat = Bcat + (size_t)N2 * H_DIM;              // H*2N     bf16 ( 8 MB)
    u16* Hbf  = Ccat + (size_t)H_DIM * N2;              // T*2N     bf16 (16 MB)
    float* Bu = (float*)(Hbf + (size_t)T_DIM * N2);     // T*2N     f32  (32 MB)
    float* car = Bu + (size_t)T_DIM * N2;               // NCHUNK*2N f32 (0.5 MB)

    cvt_u_k<<<(T_DIM * H_DIM / 4) / 256, 256, 0, stream>>>(U, Ubf);
    cvt_b_k<<<((size_t)N2 * H_DIM / 4) / 256, 256, 0, stream>>>(Bre, Bim, glog, Bcat);
    cvt_c_k<<<((size_t)H_DIM * N2 / 4) / 256, 256, 0, stream>>>(Cre, Cim, Ccat);

    gemm_nt<0><<<32 * 16, 256, 0, stream>>>(Ubf, Bcat, Bu, nullptr, nullptr);

    scan_local_k<<<(NCHUNK * N_DIM) / 256, 256, 0, stream>>>(Bu, nu, theta, car);
    scan_carry_k<<<N_DIM / 64, 256, 0, stream>>>(car, nu, theta);
    fixup_cvt_k<<<((size_t)T_DIM * N_DIM) / 256, 256, 0, stream>>>(Bu, car, nu, theta, Hbf);

    gemm_nt<1><<<32 * 16, 256, 0, stream>>>(Hbf, Ccat, Y, Dp, U);
}

// Round 3
// 127.160 us; speedup vs baseline: 16.1369x; 1.2430x over previous
//
#include <hip/hip_runtime.h>
#include <math.h>

#define T_DIM 4096
#define H_DIM 2048
#define N_DIM 1024
#define N2    2048           // 2*N (concat re/im) == H
#define KK    2048           // K of both GEMMs
#define CHUNK 64
#define NCHUNK (T_DIM / CHUNK)
#define NT    (KK / 64)      // 32 K-tiles of BK=64

using u16    = unsigned short;
using u16x4  = __attribute__((ext_vector_type(4))) u16;
using bf16x8 = __attribute__((ext_vector_type(8))) short;
using f32x4  = __attribute__((ext_vector_type(4))) float;

typedef const __attribute__((address_space(1))) u16 glob_u16;
typedef __attribute__((address_space(3))) u16 lds_u16;

__device__ inline void gload16(const u16* g, u16* l) {
    // async global->LDS: per-lane global src, wave-uniform LDS base + lane*16
    __builtin_amdgcn_global_load_lds((glob_u16*)g, (lds_u16*)l, 16, 0, 0);
}

__device__ inline u16 f2bf(float x) {   // RNE fp32->bf16
    unsigned u = __builtin_bit_cast(unsigned, x);
    u += 0x7fffu + ((u >> 16) & 1u);
    return (u16)(u >> 16);
}
__device__ inline float bf2f(u16 x) {
    return __builtin_bit_cast(float, (unsigned)x << 16);
}

// ---------------------------------------------------------------------------
// Conversion kernels
// ---------------------------------------------------------------------------
__global__ __launch_bounds__(256) void cvt_u_k(const float* __restrict__ X,
                                               u16* __restrict__ Y) {
    size_t i = ((size_t)blockIdx.x * 256 + threadIdx.x) * 4;
    float4 v = *(const float4*)(X + i);
    u16x4 o = { f2bf(v.x), f2bf(v.y), f2bf(v.z), f2bf(v.w) };
    *(u16x4*)(Y + i) = o;
}

__global__ __launch_bounds__(256) void cvt_b_k(const float* __restrict__ Bre,
                                               const float* __restrict__ Bim,
                                               const float* __restrict__ glog,
                                               u16* __restrict__ Bcat) {
    size_t i = ((size_t)blockIdx.x * 256 + threadIdx.x) * 4;
    int n = (int)(i >> 11);          // row in [0, 2048)
    size_t h = i & 2047;
    int nn = n & (N_DIM - 1);
    float g = expf(glog[nn]);
    const float* src = (n < N_DIM ? Bre : Bim) + (size_t)nn * H_DIM + h;
    float4 v = *(const float4*)src;
    u16x4 o = { f2bf(v.x * g), f2bf(v.y * g), f2bf(v.z * g), f2bf(v.w * g) };
    *(u16x4*)(Bcat + i) = o;
}

__global__ __launch_bounds__(256) void cvt_c_k(const float* __restrict__ Cre,
                                               const float* __restrict__ Cim,
                                               u16* __restrict__ Ccat) {
    size_t i = ((size_t)blockIdx.x * 256 + threadIdx.x) * 4;
    int hrow = (int)(i >> 11);
    int n = (int)(i & 2047);
    float sgn = 1.f;
    const float* src;
    if (n < N_DIM) src = Cre + (size_t)hrow * N_DIM + n;
    else { src = Cim + (size_t)hrow * N_DIM + (n - N_DIM); sgn = -1.f; }
    float4 v = *(const float4*)src;
    u16x4 o = { f2bf(v.x * sgn), f2bf(v.y * sgn), f2bf(v.z * sgn), f2bf(v.w * sgn) };
    *(u16x4*)(Ccat + i) = o;
}

// ---------------------------------------------------------------------------
// Deep-pipelined bf16 NT GEMM.  BM=256 BN=128 BK=64, 512 thr = 8 waves (4x2),
// per-wave 64x64 via 4x4 frags of mfma_f32_16x16x32_bf16.
// A triple-buffered (3x32KB), B double-buffered (2x16KB) = 128KB LDS.
// LDS XOR-swizzle: LDS[row][kc ^ (row&7)] holds G[row][kc]  (kc = 16B chunk).
// Per iter: vmcnt(4) + 1 barrier + stage B(t+1),A(t+2) + 16 ds_read + 32 MFMA.
// EPI=1: C += D[col]*bf2f(Ubf[row][col])
// ---------------------------------------------------------------------------
template <int EPI>
__global__ __launch_bounds__(512, 2) void gemm_pipe(
    const u16* __restrict__ A, const u16* __restrict__ B,
    float* __restrict__ C, const float* __restrict__ D,
    const u16* __restrict__ Ubf)
{
    __shared__ u16 lds[65536];   // A bufs @ 0,16384,32768 ; B bufs @ 49152,+8192

    const int tid  = threadIdx.x;
    const int wave = tid >> 6, lane = tid & 63;
    const int bm = blockIdx.x >> 4;          // 0..15  (rows of A)
    const int bn = blockIdx.x & 15;          // 0..15  (rows of B = out cols)
    const size_t row0 = (size_t)bm * 256;
    const size_t col0 = (size_t)bn * 128;
    const int wr = wave >> 1, wc = wave & 1; // 4x2 wave grid, per-wave 64x64
    const int fr = lane & 15, fq = lane >> 4;

    // staging: thread covers row (u*64 + tid>>3), source col-chunk pre-swizzled
    const int srow = tid >> 3;               // 0..63
    const int skc  = (tid & 7) ^ (srow & 7);
    const u16* aSrc = A + (row0 + srow) * KK + skc * 8;
    const u16* bSrc = B + (col0 + srow) * KK + skc * 8;

    // frag-read bases (u16 indices), swizzled: slot = (kk*4+fq) ^ (fr&7)
    const int aBase = (wr * 64 + fr) * 64;   // + m*1024 + swz
    const int bBase = (wc * 64 + fr) * 64;   // + n*1024 + swz
    const int swz0 = ((fq)     ^ (fr & 7)) * 8;
    const int swz1 = ((4 + fq) ^ (fr & 7)) * 8;

    f32x4 acc[4][4] = {};

    auto STAGE_A = [&](int buf, int kt) {
#pragma unroll
        for (int u = 0; u < 4; ++u)
            gload16(aSrc + (size_t)u * 64 * KK + kt * 64,
                    &lds[buf * 16384 + u * 4096 + wave * 512]);
    };
    auto STAGE_B = [&](int buf, int kt) {
#pragma unroll
        for (int u = 0; u < 2; ++u)
            gload16(bSrc + (size_t)u * 64 * KK + kt * 64,
                    &lds[49152 + buf * 8192 + u * 4096 + wave * 512]);
    };
    auto COMPUTE = [&](int abuf, int bbuf) {
        const u16* Ab = &lds[abuf * 16384];
        const u16* Bb = &lds[49152 + bbuf * 8192];
        bf16x8 af[2][4], bfv[2][4];
#pragma unroll
        for (int m = 0; m < 4; ++m) {
            af[0][m] = *(const bf16x8*)&Ab[aBase + m * 1024 + swz0];
            af[1][m] = *(const bf16x8*)&Ab[aBase + m * 1024 + swz1];
        }
#pragma unroll
        for (int n = 0; n < 4; ++n) {
            bfv[0][n] = *(const bf16x8*)&Bb[bBase + n * 1024 + swz0];
            bfv[1][n] = *(const bf16x8*)&Bb[bBase + n * 1024 + swz1];
        }
        __builtin_amdgcn_s_setprio(1);
#pragma unroll
        for (int kk = 0; kk < 2; ++kk)
#pragma unroll
            for (int m = 0; m < 4; ++m)
#pragma unroll
                for (int n = 0; n < 4; ++n)
                    acc[m][n] = __builtin_amdgcn_mfma_f32_16x16x32_bf16(
                        af[kk][m], bfv[kk][n], acc[m][n], 0, 0, 0);
        __builtin_amdgcn_s_setprio(0);
    };

    // prologue: issue A(0), B(0), A(1)  -> 10 loads outstanding
    STAGE_A(0, 0); STAGE_B(0, 0); STAGE_A(1, 1);

    int a_cur = 0;                           // t % 3
    for (int t = 0; t < NT - 1; ++t) {
        // wait: my A(t) and B(t) landed (leaves A(t+1)'s 4 loads in flight)
        asm volatile("s_waitcnt vmcnt(4)" ::: "memory");
        __builtin_amdgcn_s_barrier();        // all waves: loads landed, prior reads done
        STAGE_B((t + 1) & 1, t + 1);
        if (t + 2 < NT) {
            int a_nxt = a_cur + 2; if (a_nxt >= 3) a_nxt -= 3;
            STAGE_A(a_nxt, t + 2);
        }
        COMPUTE(a_cur, t & 1);
        ++a_cur; if (a_cur == 3) a_cur = 0;
    }
    // final tile (no staging)
    asm volatile("s_waitcnt vmcnt(0)" ::: "memory");
    __builtin_amdgcn_s_barrier();
    COMPUTE(a_cur, (NT - 1) & 1);

    // epilogue: C/D layout col=lane&15, row=(lane>>4)*4+reg  [m89/m91]
    const int crow = (int)row0 + wr * 64 + fq * 4;
    const int ccol = (int)col0 + wc * 64 + fr;
    float dc[4];
    if constexpr (EPI) {
#pragma unroll
        for (int n = 0; n < 4; ++n) dc[n] = D[ccol + n * 16];
    }
#pragma unroll
    for (int m = 0; m < 4; ++m)
#pragma unroll
        for (int n = 0; n < 4; ++n) {
            int cc = ccol + n * 16;
#pragma unroll
            for (int j = 0; j < 4; ++j) {
                int r = crow + m * 16 + j;
                size_t p = (size_t)r * N2 + cc;
                float v = acc[m][n][j];
                if constexpr (EPI) v += dc[n] * bf2f(Ubf[p]);
                C[p] = v;
            }
        }
}

// ---------------------------------------------------------------------------
// Scan over [T, 2N] layout: re at col c, im at col c+N.  (unchanged, verified)
// ---------------------------------------------------------------------------
__global__ __launch_bounds__(256) void scan_local_k(float* __restrict__ Bu,
                                                    const float* __restrict__ nu,
                                                    const float* __restrict__ theta,
                                                    float* __restrict__ car) {
    int idx = blockIdx.x * 256 + threadIdx.x;   // 0 .. NCHUNK*N-1
    int chan = idx & (N_DIM - 1);
    int chunk = idx >> 10;
    float a = expf(nu[chan]), b = expf(theta[chan]);
    float m = expf(-a), s, c;
    __sincosf(b, &s, &c);
    float lr = m * c, li = m * s;
    float hr = 0.f, hi = 0.f;
    size_t base = (size_t)chunk * CHUNK * N2 + chan;
    for (int i = 0; i < CHUNK; ++i) {
        size_t p = base + (size_t)i * N2;
        float br = Bu[p], bi = Bu[p + N_DIM];
        float nr = fmaf(lr, hr, fmaf(-li, hi, br));
        float ni = fmaf(lr, hi, fmaf(li, hr, bi));
        hr = nr; hi = ni;
        Bu[p] = hr; Bu[p + N_DIM] = hi;
    }
    car[(size_t)chunk * N2 + chan] = hr;
    car[(size_t)chunk * N2 + N_DIM + chan] = hi;
}

__global__ __launch_bounds__(256) void scan_carry_k(float* __restrict__ car,
                                                    const float* __restrict__ nu,
                                                    const float* __restrict__ theta) {
    __shared__ float sR[NCHUNK][65], sI[NCHUNK][65];
    int tid = threadIdx.x;
    int chan0 = blockIdx.x * 64;
    for (int i = tid; i < NCHUNK * 64; i += 256) {
        int ck = i >> 6, c = i & 63;
        sR[ck][c] = car[(size_t)ck * N2 + chan0 + c];
        sI[ck][c] = car[(size_t)ck * N2 + N_DIM + chan0 + c];
    }
    __syncthreads();
    if (tid < 64) {
        int chan = chan0 + tid;
        float a = expf(nu[chan]), b = expf(theta[chan]);
        float m = expf(-(float)CHUNK * a), s, c;   // lambda^CHUNK closed-form
        __sincosf((float)CHUNK * b, &s, &c);
        float lr = m * c, li = m * s;
        float hr = sR[0][tid], hi = sI[0][tid];
        for (int ck = 1; ck < NCHUNK; ++ck) {
            float nr = fmaf(lr, hr, fmaf(-li, hi, sR[ck][tid]));
            float ni = fmaf(lr, hi, fmaf(li, hr, sI[ck][tid]));
            hr = nr; hi = ni;
            sR[ck][tid] = hr; sI[ck][tid] = hi;
        }
    }
    __syncthreads();
    for (int i = tid; i < NCHUNK * 64; i += 256) {
        int ck = i >> 6, c = i & 63;
        car[(size_t)ck * N2 + chan0 + c] = sR[ck][c];
        car[(size_t)ck * N2 + N_DIM + chan0 + c] = sI[ck][c];
    }
}

// fixup h[t] = lambda^{(t%CHUNK)+1}*carry[chunk-1] + local[t], write bf16 h
__global__ __launch_bounds__(256) void fixup_cvt_k(const float* __restrict__ Bu,
                                                   const float* __restrict__ car,
                                                   const float* __restrict__ nu,
                                                   const float* __restrict__ theta,
                                                   u16* __restrict__ Hbf) {
    size_t idx = (size_t)blockIdx.x * 256 + threadIdx.x;  // 0 .. T*N-1
    int chan = (int)(idx & (N_DIM - 1));
    size_t t = idx >> 10;
    int chunk = (int)(t >> 6);
    size_t p = t * N2 + chan;
    float hr = Bu[p], hi = Bu[p + N_DIM];
    if (chunk > 0) {
        float pf = (float)((t & (CHUNK - 1)) + 1);
        float a = expf(nu[chan]), b = expf(theta[chan]);
        float m = expf(-pf * a), s, c;
        __sincosf(pf * b, &s, &c);
        float lr = m * c, li = m * s;
        size_t cp = (size_t)(chunk - 1) * N2 + chan;
        float cr = car[cp], ci = car[cp + N_DIM];
        hr += lr * cr - li * ci;
        hi += lr * ci + li * cr;
    }
    Hbf[p] = f2bf(hr);
    Hbf[p + N_DIM] = f2bf(hi);
}

extern "C" void kernel_launch(void* const* d_in, const int* in_sizes, int n_in,
                              void* d_out, int out_size, void* d_ws, size_t ws_size,
                              hipStream_t stream) {
    const float* U     = (const float*)d_in[0];   // [T,H]
    const float* nu    = (const float*)d_in[1];   // [N]
    const float* theta = (const float*)d_in[2];   // [N]
    const float* glog  = (const float*)d_in[3];   // [N]
    const float* Bre   = (const float*)d_in[4];   // [N,H]
    const float* Bim   = (const float*)d_in[5];   // [N,H]
    const float* Cre   = (const float*)d_in[6];   // [H,N]
    const float* Cim   = (const float*)d_in[7];   // [H,N]
    const float* Dp    = (const float*)d_in[8];   // [H]
    float* Y = (float*)d_out;

    u16* Ubf  = (u16*)d_ws;                             // T*H       bf16
    u16* Bcat = Ubf + (size_t)T_DIM * H_DIM;            // 2N*H      bf16
    u16* Ccat = Bcat + (size_t)N2 * H_DIM;              // H*2N      bf16
    u16* Hbf  = Ccat + (size_t)H_DIM * N2;              // T*2N      bf16
    float* Bu = (float*)(Hbf + (size_t)T_DIM * N2);     // T*2N      f32
    float* car = Bu + (size_t)T_DIM * N2;               // NCHUNK*2N f32

    cvt_u_k<<<(T_DIM * H_DIM / 4) / 256, 256, 0, stream>>>(U, Ubf);
    cvt_b_k<<<((size_t)N2 * H_DIM / 4) / 256, 256, 0, stream>>>(Bre, Bim, glog, Bcat);
    cvt_c_k<<<((size_t)H_DIM * N2 / 4) / 256, 256, 0, stream>>>(Cre, Cim, Ccat);

    gemm_pipe<0><<<256, 512, 0, stream>>>(Ubf, Bcat, Bu, nullptr, nullptr);

    scan_local_k<<<(NCHUNK * N_DIM) / 256, 256, 0, stream>>>(Bu, nu, theta, car);
    scan_carry_k<<<N_DIM / 64, 256, 0, stream>>>(car, nu, theta);
    fixup_cvt_k<<<((size_t)T_DIM * N_DIM) / 256, 256, 0, stream>>>(Bu, car, nu, theta, Hbf);

    gemm_pipe<1><<<256, 512, 0, stream>>>(Hbf, Ccat, Y, Dp, Ubf);
}

// Round 4
// 121.749 us; speedup vs baseline: 16.8540x; 1.0444x over previous
//
#include <hip/hip_runtime.h>
#include <math.h>

#define T_DIM 4096
#define H_DIM 2048
#define N_DIM 1024
#define N2    2048           // 2*N (concat re/im) == H
#define KK    2048           // K of both GEMMs
#define CHUNK 64
#define NCHUNK (T_DIM / CHUNK)
#define NT    (KK / 64)      // 32 K-tiles of BK=64

using u16    = unsigned short;
using u16x4  = __attribute__((ext_vector_type(4))) u16;
using bf16x8 = __attribute__((ext_vector_type(8))) short;
using f32x4  = __attribute__((ext_vector_type(4))) float;

typedef const __attribute__((address_space(1))) u16 glob_u16;
typedef __attribute__((address_space(3))) u16 lds_u16;

__device__ inline void gload16(const u16* g, u16* l) {
    // async global->LDS: per-lane global src, wave-uniform LDS base + lane*16
    __builtin_amdgcn_global_load_lds((glob_u16*)g, (lds_u16*)l, 16, 0, 0);
}

__device__ inline u16 f2bf(float x) {   // RNE fp32->bf16
    unsigned u = __builtin_bit_cast(unsigned, x);
    u += 0x7fffu + ((u >> 16) & 1u);
    return (u16)(u >> 16);
}
__device__ inline float bf2f(u16 x) {
    return __builtin_bit_cast(float, (unsigned)x << 16);
}

// ---------------------------------------------------------------------------
// Conversion kernels
// ---------------------------------------------------------------------------
__global__ __launch_bounds__(256) void cvt_u_k(const float* __restrict__ X,
                                               u16* __restrict__ Y) {
    size_t i = ((size_t)blockIdx.x * 256 + threadIdx.x) * 4;
    float4 v = *(const float4*)(X + i);
    u16x4 o = { f2bf(v.x), f2bf(v.y), f2bf(v.z), f2bf(v.w) };
    *(u16x4*)(Y + i) = o;
}

__global__ __launch_bounds__(256) void cvt_b_k(const float* __restrict__ Bre,
                                               const float* __restrict__ Bim,
                                               const float* __restrict__ glog,
                                               u16* __restrict__ Bcat) {
    size_t i = ((size_t)blockIdx.x * 256 + threadIdx.x) * 4;
    int n = (int)(i >> 11);          // row in [0, 2048)
    size_t h = i & 2047;
    int nn = n & (N_DIM - 1);
    float g = expf(glog[nn]);
    const float* src = (n < N_DIM ? Bre : Bim) + (size_t)nn * H_DIM + h;
    float4 v = *(const float4*)src;
    u16x4 o = { f2bf(v.x * g), f2bf(v.y * g), f2bf(v.z * g), f2bf(v.w * g) };
    *(u16x4*)(Bcat + i) = o;
}

__global__ __launch_bounds__(256) void cvt_c_k(const float* __restrict__ Cre,
                                               const float* __restrict__ Cim,
                                               u16* __restrict__ Ccat) {
    size_t i = ((size_t)blockIdx.x * 256 + threadIdx.x) * 4;
    int hrow = (int)(i >> 11);
    int n = (int)(i & 2047);
    float sgn = 1.f;
    const float* src;
    if (n < N_DIM) src = Cre + (size_t)hrow * N_DIM + n;
    else { src = Cim + (size_t)hrow * N_DIM + (n - N_DIM); sgn = -1.f; }
    float4 v = *(const float4*)src;
    u16x4 o = { f2bf(v.x * sgn), f2bf(v.y * sgn), f2bf(v.z * sgn), f2bf(v.w * sgn) };
    *(u16x4*)(Ccat + i) = o;
}

// ---------------------------------------------------------------------------
// Phase-scheduled bf16 NT GEMM (m201-style rhythm on BM=256 BN=128 BK=64).
// 512 thr = 8 waves (4x2), per-wave 64x64 via 4x4 frags of 16x16x32 MFMA.
// A triple-buffered (3x32KB, staged 2 tiles ahead), B double-buffered
// (2x16KB, staged 1 ahead) = 128KB LDS. Per K-tile: 2 phases, each
// {8 ds_read || 2-4 gloads -> barrier -> lgkmcnt(0) -> setprio+16 MFMA ->
//  barrier}; counted vmcnt(4) only at tile boundary.
// LDS XOR-swizzle both-sides (pre-swizzled global src + swizzled read).
// EPI=1: C += D[col]*bf2f(Ubf[row][col])
// ---------------------------------------------------------------------------
template <int EPI>
__global__ __launch_bounds__(512, 2) void gemm_pipe(
    const u16* __restrict__ A, const u16* __restrict__ B,
    float* __restrict__ C, const float* __restrict__ D,
    const u16* __restrict__ Ubf)
{
    __shared__ u16 lds[65536];   // A bufs @ 0,16384,32768 ; B bufs @ 49152,+8192

    const int tid  = threadIdx.x;
    const int wave = tid >> 6, lane = tid & 63;
    // XCD-aware swizzle: 256 blocks, 8 XCDs -> each XCD gets 32 contiguous
    // tile-ids = 2 full bm rows (A-panel 2MB resident in that XCD's L2).
    const int nbid = (blockIdx.x & 7) * 32 + (blockIdx.x >> 3);
    const int bm = nbid >> 4;                // 0..15  (rows of A)
    const int bn = nbid & 15;                // 0..15  (rows of B = out cols)
    const size_t row0 = (size_t)bm * 256;
    const size_t col0 = (size_t)bn * 128;
    const int wr = wave >> 1, wc = wave & 1; // 4x2 wave grid, per-wave 64x64
    const int fr = lane & 15, fq = lane >> 4;

    // staging: thread covers row (u*64 + tid>>3), source col-chunk pre-swizzled
    const int srow = tid >> 3;               // 0..63
    const int skc  = (tid & 7) ^ (srow & 7);
    const u16* aSrc = A + (row0 + srow) * KK + skc * 8;
    const u16* bSrc = B + (col0 + srow) * KK + skc * 8;

    // frag-read bases (u16 indices), swizzled: slot = (kk*4+fq) ^ (fr&7)
    const int aBase = (wr * 64 + fr) * 64;   // + m*1024 + swz
    const int bBase = (wc * 64 + fr) * 64;   // + n*1024 + swz
    const int swzk[2] = { ((fq) ^ (fr & 7)) * 8, ((4 + fq) ^ (fr & 7)) * 8 };

    f32x4 acc[4][4] = {};

    auto STAGE_A = [&](int buf, int kt) {
#pragma unroll
        for (int u = 0; u < 4; ++u)
            gload16(aSrc + (size_t)u * 64 * KK + kt * 64,
                    &lds[buf * 16384 + u * 4096 + wave * 512]);
    };
    auto STAGE_B = [&](int buf, int kt) {
#pragma unroll
        for (int u = 0; u < 2; ++u)
            gload16(bSrc + (size_t)u * 64 * KK + kt * 64,
                    &lds[49152 + buf * 8192 + u * 4096 + wave * 512]);
    };

    // prologue: issue A(0), B(0), A(1) -> 10 loads; validate tile 0
    STAGE_A(0, 0); STAGE_B(0, 0); STAGE_A(1, 1);
    asm volatile("s_waitcnt vmcnt(4)\n\ts_barrier" ::: "memory");

    int a_cur = 0;                           // t % 3
#pragma unroll 2
    for (int t = 0; t < NT; ++t) {
        const u16* Ab = &lds[a_cur * 16384];
        const u16* Bb = &lds[49152 + (t & 1) * 8192];
        bf16x8 af[4], bfv[4];

        // ---------------- phase 0 (kk = 0) ----------------
#pragma unroll
        for (int m = 0; m < 4; ++m)
            af[m] = *(const bf16x8*)&Ab[aBase + m * 1024 + swzk[0]];
#pragma unroll
        for (int n = 0; n < 4; ++n)
            bfv[n] = *(const bf16x8*)&Bb[bBase + n * 1024 + swzk[0]];
        if (t + 1 < NT) STAGE_B((t + 1) & 1, t + 1);
        asm volatile("s_barrier\n\ts_waitcnt lgkmcnt(0)" ::: "memory");
        __builtin_amdgcn_s_setprio(1);
#pragma unroll
        for (int m = 0; m < 4; ++m)
#pragma unroll
            for (int n = 0; n < 4; ++n)
                acc[m][n] = __builtin_amdgcn_mfma_f32_16x16x32_bf16(
                    af[m], bfv[n], acc[m][n], 0, 0, 0);
        __builtin_amdgcn_s_setprio(0);
        asm volatile("s_barrier" ::: "memory");

        // ---------------- phase 1 (kk = 1) ----------------
#pragma unroll
        for (int m = 0; m < 4; ++m)
            af[m] = *(const bf16x8*)&Ab[aBase + m * 1024 + swzk[1]];
#pragma unroll
        for (int n = 0; n < 4; ++n)
            bfv[n] = *(const bf16x8*)&Bb[bBase + n * 1024 + swzk[1]];
        if (t + 2 < NT) {
            int a_nxt = a_cur - 1; if (a_nxt < 0) a_nxt = 2;   // (t+2) % 3
            STAGE_A(a_nxt, t + 2);
        }
        // tile-boundary: validate buffers of tile t+1 (counted, never 0 mid-loop)
        if (t + 2 < NT)
            asm volatile("s_waitcnt vmcnt(4)\n\ts_barrier\n\ts_waitcnt lgkmcnt(0)" ::: "memory");
        else if (t + 1 < NT)
            asm volatile("s_waitcnt vmcnt(0)\n\ts_barrier\n\ts_waitcnt lgkmcnt(0)" ::: "memory");
        else
            asm volatile("s_barrier\n\ts_waitcnt lgkmcnt(0)" ::: "memory");
        __builtin_amdgcn_s_setprio(1);
#pragma unroll
        for (int m = 0; m < 4; ++m)
#pragma unroll
            for (int n = 0; n < 4; ++n)
                acc[m][n] = __builtin_amdgcn_mfma_f32_16x16x32_bf16(
                    af[m], bfv[n], acc[m][n], 0, 0, 0);
        __builtin_amdgcn_s_setprio(0);
        asm volatile("s_barrier" ::: "memory");

        ++a_cur; if (a_cur == 3) a_cur = 0;
    }

    // epilogue: C/D layout col=lane&15, row=(lane>>4)*4+reg  [m89/m91]
    const int crow = (int)row0 + wr * 64 + fq * 4;
    const int ccol = (int)col0 + wc * 64 + fr;
    float dc[4];
    if constexpr (EPI) {
#pragma unroll
        for (int n = 0; n < 4; ++n) dc[n] = D[ccol + n * 16];
    }
#pragma unroll
    for (int m = 0; m < 4; ++m)
#pragma unroll
        for (int n = 0; n < 4; ++n) {
            int cc = ccol + n * 16;
#pragma unroll
            for (int j = 0; j < 4; ++j) {
                int r = crow + m * 16 + j;
                size_t p = (size_t)r * N2 + cc;
                float v = acc[m][n][j];
                if constexpr (EPI) v += dc[n] * bf2f(Ubf[p]);
                C[p] = v;
            }
        }
}

// ---------------------------------------------------------------------------
// Scan, recompute scheme.  Bu layout [T, 2N]: re at col c, im at col c+N.
// pass 1: per-(chunk,chan) local carry only (read Bu once, no Bu writes)
// ---------------------------------------------------------------------------
__global__ __launch_bounds__(256) void carry_pass_k(const float* __restrict__ Bu,
                                                    const float* __restrict__ nu,
                                                    const float* __restrict__ theta,
                                                    float* __restrict__ car) {
    int idx = blockIdx.x * 256 + threadIdx.x;   // 0 .. NCHUNK*N-1
    int chan = idx & (N_DIM - 1);
    int chunk = idx >> 10;
    float a = expf(nu[chan]), b = expf(theta[chan]);
    float m = expf(-a), s, c;
    __sincosf(b, &s, &c);
    float lr = m * c, li = m * s;
    float hr = 0.f, hi = 0.f;
    size_t base = (size_t)chunk * CHUNK * N2 + chan;
    for (int i = 0; i < CHUNK; ++i) {
        size_t p = base + (size_t)i * N2;
        float br = Bu[p], bi = Bu[p + N_DIM];
        float nr = fmaf(lr, hr, fmaf(-li, hi, br));
        float ni = fmaf(lr, hi, fmaf(li, hr, bi));
        hr = nr; hi = ni;
    }
    car[(size_t)chunk * N2 + chan] = hr;
    car[(size_t)chunk * N2 + N_DIM + chan] = hi;
}

// pass 2: combine carries across chunks (per channel, lambda^CHUNK closed form)
__global__ __launch_bounds__(256) void scan_carry_k(float* __restrict__ car,
                                                    const float* __restrict__ nu,
                                                    const float* __restrict__ theta) {
    __shared__ float sR[NCHUNK][65], sI[NCHUNK][65];
    int tid = threadIdx.x;
    int chan0 = blockIdx.x * 64;
    for (int i = tid; i < NCHUNK * 64; i += 256) {
        int ck = i >> 6, c = i & 63;
        sR[ck][c] = car[(size_t)ck * N2 + chan0 + c];
        sI[ck][c] = car[(size_t)ck * N2 + N_DIM + chan0 + c];
    }
    __syncthreads();
    if (tid < 64) {
        int chan = chan0 + tid;
        float a = expf(nu[chan]), b = expf(theta[chan]);
        float m = expf(-(float)CHUNK * a), s, c;
        __sincosf((float)CHUNK * b, &s, &c);
        float lr = m * c, li = m * s;
        float hr = sR[0][tid], hi = sI[0][tid];
        for (int ck = 1; ck < NCHUNK; ++ck) {
            float nr = fmaf(lr, hr, fmaf(-li, hi, sR[ck][tid]));
            float ni = fmaf(lr, hi, fmaf(li, hr, sI[ck][tid]));
            hr = nr; hi = ni;
            sR[ck][tid] = hr; sI[ck][tid] = hi;
        }
    }
    __syncthreads();
    for (int i = tid; i < NCHUNK * 64; i += 256) {
        int ck = i >> 6, c = i & 63;
        car[(size_t)ck * N2 + chan0 + c] = sR[ck][c];
        car[(size_t)ck * N2 + N_DIM + chan0 + c] = sI[ck][c];
    }
}

// pass 3: recompute local scan seeded with combined carry, write bf16 h
__global__ __launch_bounds__(256) void scan_out_k(const float* __restrict__ Bu,
                                                  const float* __restrict__ car,
                                                  const float* __restrict__ nu,
                                                  const float* __restrict__ theta,
                                                  u16* __restrict__ Hbf) {
    int idx = blockIdx.x * 256 + threadIdx.x;   // 0 .. NCHUNK*N-1
    int chan = idx & (N_DIM - 1);
    int chunk = idx >> 10;
    float a = expf(nu[chan]), b = expf(theta[chan]);
    float m = expf(-a), s, c;
    __sincosf(b, &s, &c);
    float lr = m * c, li = m * s;
    float hr = 0.f, hi = 0.f;
    if (chunk > 0) {
        size_t cp = (size_t)(chunk - 1) * N2 + chan;
        hr = car[cp]; hi = car[cp + N_DIM];
    }
    size_t base = (size_t)chunk * CHUNK * N2 + chan;
    for (int i = 0; i < CHUNK; ++i) {
        size_t p = base + (size_t)i * N2;
        float br = Bu[p], bi = Bu[p + N_DIM];
        float nr = fmaf(lr, hr, fmaf(-li, hi, br));
        float ni = fmaf(lr, hi, fmaf(li, hr, bi));
        hr = nr; hi = ni;
        Hbf[p] = f2bf(hr);
        Hbf[p + N_DIM] = f2bf(hi);
    }
}

extern "C" void kernel_launch(void* const* d_in, const int* in_sizes, int n_in,
                              void* d_out, int out_size, void* d_ws, size_t ws_size,
                              hipStream_t stream) {
    const float* U     = (const float*)d_in[0];   // [T,H]
    const float* nu    = (const float*)d_in[1];   // [N]
    const float* theta = (const float*)d_in[2];   // [N]
    const float* glog  = (const float*)d_in[3];   // [N]
    const float* Bre   = (const float*)d_in[4];   // [N,H]
    const float* Bim   = (const float*)d_in[5];   // [N,H]
    const float* Cre   = (const float*)d_in[6];   // [H,N]
    const float* Cim   = (const float*)d_in[7];   // [H,N]
    const float* Dp    = (const float*)d_in[8];   // [H]
    float* Y = (float*)d_out;

    u16* Ubf  = (u16*)d_ws;                             // T*H       bf16
    u16* Bcat = Ubf + (size_t)T_DIM * H_DIM;            // 2N*H      bf16
    u16* Ccat = Bcat + (size_t)N2 * H_DIM;              // H*2N      bf16
    u16* Hbf  = Ccat + (size_t)H_DIM * N2;              // T*2N      bf16
    float* Bu = (float*)(Hbf + (size_t)T_DIM * N2);     // T*2N      f32
    float* car = Bu + (size_t)T_DIM * N2;               // NCHUNK*2N f32

    cvt_u_k<<<(T_DIM * H_DIM / 4) / 256, 256, 0, stream>>>(U, Ubf);
    cvt_b_k<<<((size_t)N2 * H_DIM / 4) / 256, 256, 0, stream>>>(Bre, Bim, glog, Bcat);
    cvt_c_k<<<((size_t)H_DIM * N2 / 4) / 256, 256, 0, stream>>>(Cre, Cim, Ccat);

    gemm_pipe<0><<<256, 512, 0, stream>>>(Ubf, Bcat, Bu, nullptr, nullptr);

    carry_pass_k<<<(NCHUNK * N_DIM) / 256, 256, 0, stream>>>(Bu, nu, theta, car);
    scan_carry_k<<<N_DIM / 64, 256, 0, stream>>>(car, nu, theta);
    scan_out_k<<<(NCHUNK * N_DIM) / 256, 256, 0, stream>>>(Bu, car, nu, theta, Hbf);

    gemm_pipe<1><<<256, 512, 0, stream>>>(Hbf, Ccat, Y, Dp, Ubf);
}

// Round 5
// 114.893 us; speedup vs baseline: 17.8598x; 1.0597x over previous
//
#include <hip/hip_runtime.h>
#include <math.h>

#define T_DIM 4096
#define H_DIM 2048
#define N_DIM 1024
#define N2    2048           // 2*N (concat re/im) == H
#define KK    2048           // K of both GEMMs
#define CHUNK 64
#define NCHUNK (T_DIM / CHUNK)
#define NT    (KK / 64)      // 32 K-tiles of BK=64

using u16    = unsigned short;
using u16x4  = __attribute__((ext_vector_type(4))) u16;
using bf16x8 = __attribute__((ext_vector_type(8))) short;
using f32x4  = __attribute__((ext_vector_type(4))) float;

typedef const __attribute__((address_space(1))) u16 glob_u16;
typedef __attribute__((address_space(3))) u16 lds_u16;

__device__ inline void gload16(const u16* g, u16* l) {
    // async global->LDS: per-lane global src, wave-uniform LDS base + lane*16
    __builtin_amdgcn_global_load_lds((glob_u16*)g, (lds_u16*)l, 16, 0, 0);
}

__device__ inline u16 f2bf(float x) {   // RNE fp32->bf16
    unsigned u = __builtin_bit_cast(unsigned, x);
    u += 0x7fffu + ((u >> 16) & 1u);
    return (u16)(u >> 16);
}
__device__ inline float bf2f(u16 x) {
    return __builtin_bit_cast(float, (unsigned)x << 16);
}

// ---------------------------------------------------------------------------
// Conversion kernels
// ---------------------------------------------------------------------------
__global__ __launch_bounds__(256) void cvt_u_k(const float* __restrict__ X,
                                               u16* __restrict__ Y) {
    size_t i = ((size_t)blockIdx.x * 256 + threadIdx.x) * 4;
    float4 v = *(const float4*)(X + i);
    u16x4 o = { f2bf(v.x), f2bf(v.y), f2bf(v.z), f2bf(v.w) };
    *(u16x4*)(Y + i) = o;
}

__global__ __launch_bounds__(256) void cvt_b_k(const float* __restrict__ Bre,
                                               const float* __restrict__ Bim,
                                               const float* __restrict__ glog,
                                               u16* __restrict__ Bcat) {
    size_t i = ((size_t)blockIdx.x * 256 + threadIdx.x) * 4;
    int n = (int)(i >> 11);          // row in [0, 2048)
    size_t h = i & 2047;
    int nn = n & (N_DIM - 1);
    float g = expf(glog[nn]);
    const float* src = (n < N_DIM ? Bre : Bim) + (size_t)nn * H_DIM + h;
    float4 v = *(const float4*)src;
    u16x4 o = { f2bf(v.x * g), f2bf(v.y * g), f2bf(v.z * g), f2bf(v.w * g) };
    *(u16x4*)(Bcat + i) = o;
}

__global__ __launch_bounds__(256) void cvt_c_k(const float* __restrict__ Cre,
                                               const float* __restrict__ Cim,
                                               u16* __restrict__ Ccat) {
    size_t i = ((size_t)blockIdx.x * 256 + threadIdx.x) * 4;
    int hrow = (int)(i >> 11);
    int n = (int)(i & 2047);
    float sgn = 1.f;
    const float* src;
    if (n < N_DIM) src = Cre + (size_t)hrow * N_DIM + n;
    else { src = Cim + (size_t)hrow * N_DIM + (n - N_DIM); sgn = -1.f; }
    float4 v = *(const float4*)src;
    u16x4 o = { f2bf(v.x * sgn), f2bf(v.y * sgn), f2bf(v.z * sgn), f2bf(v.w * sgn) };
    *(u16x4*)(Ccat + i) = o;
}

// ---------------------------------------------------------------------------
// Fragment-pipelined bf16 NT GEMM.  BM=256 BN=128 BK=64, 512 thr = 8 waves
// (4x2), per-wave 64x64 via 4x4 frags of mfma_f32_16x16x32_bf16.
// A triple-buffered (3x32KB, staged 2 ahead), B double-buffered (2x16KB,
// staged 1 ahead) = 128KB LDS.  One barrier + counted vmcnt per K-tile.
// KEY: ds_reads always fetch the NEXT phase's fragments, so LDS service
// hides under the current phase's MFMA execution (no lgkm-before-MFMA stall).
// LDS XOR-swizzle both-sides (pre-swizzled global src + swizzled read).
// EPI=1: C += D[col]*bf2f(Ubf[row][col])
// ---------------------------------------------------------------------------
template <int EPI>
__global__ __launch_bounds__(512, 1) void gemm_pipe(
    const u16* __restrict__ A, const u16* __restrict__ B,
    float* __restrict__ C, const float* __restrict__ D,
    const u16* __restrict__ Ubf)
{
    __shared__ u16 lds[65536];   // A bufs @ 0,16384,32768 ; B bufs @ 49152,+8192

    const int tid  = threadIdx.x;
    const int wave = tid >> 6, lane = tid & 63;
    // XCD-aware swizzle: 256 blocks, 8 XCDs -> each XCD gets 2 contiguous bm rows
    const int nbid = (blockIdx.x & 7) * 32 + (blockIdx.x >> 3);
    const int bm = nbid >> 4;                // 0..15
    const int bn = nbid & 15;                // 0..15
    const size_t row0 = (size_t)bm * 256;
    const size_t col0 = (size_t)bn * 128;
    const int wr = wave >> 1, wc = wave & 1; // 4x2 wave grid, per-wave 64x64
    const int fr = lane & 15, fq = lane >> 4;

    // staging: thread covers row (u*64 + tid>>3), source col-chunk pre-swizzled
    const int srow = tid >> 3;               // 0..63
    const int skc  = (tid & 7) ^ (srow & 7);
    const u16* aSrc = A + (row0 + srow) * KK + skc * 8;
    const u16* bSrc = B + (col0 + srow) * KK + skc * 8;

    // frag-read bases (u16 indices), swizzled: slot = (kk*4+fq) ^ (fr&7)
    const int aBase = (wr * 64 + fr) * 64;   // + m*1024 + swz
    const int bBase = (wc * 64 + fr) * 64;   // + n*1024 + swz
    const int swz0 = ((fq)     ^ (fr & 7)) * 8;
    const int swz1 = ((4 + fq) ^ (fr & 7)) * 8;

    f32x4 acc[4][4] = {};

    auto STAGE_A = [&](int buf, int kt) {
#pragma unroll
        for (int u = 0; u < 4; ++u)
            gload16(aSrc + (size_t)u * 64 * KK + kt * 64,
                    &lds[buf * 16384 + u * 4096 + wave * 512]);
    };
    auto STAGE_B = [&](int buf, int kt) {
#pragma unroll
        for (int u = 0; u < 2; ++u)
            gload16(bSrc + (size_t)u * 64 * KK + kt * 64,
                    &lds[49152 + buf * 8192 + u * 4096 + wave * 512]);
    };

    bf16x8 fa[4], fb[4], ga[4], gb[4];       // named ping-pong frag sets

    auto READ_F = [&](const u16* Ab, const u16* Bb, int swz) {
#pragma unroll
        for (int m = 0; m < 4; ++m) fa[m] = *(const bf16x8*)&Ab[aBase + m * 1024 + swz];
#pragma unroll
        for (int n = 0; n < 4; ++n) fb[n] = *(const bf16x8*)&Bb[bBase + n * 1024 + swz];
    };
    auto READ_G = [&](const u16* Ab, const u16* Bb, int swz) {
#pragma unroll
        for (int m = 0; m < 4; ++m) ga[m] = *(const bf16x8*)&Ab[aBase + m * 1024 + swz];
#pragma unroll
        for (int n = 0; n < 4; ++n) gb[n] = *(const bf16x8*)&Bb[bBase + n * 1024 + swz];
    };
    auto MFMA_F = [&]() {
        __builtin_amdgcn_s_setprio(1);
#pragma unroll
        for (int m = 0; m < 4; ++m)
#pragma unroll
            for (int n = 0; n < 4; ++n)
                acc[m][n] = __builtin_amdgcn_mfma_f32_16x16x32_bf16(
                    fa[m], fb[n], acc[m][n], 0, 0, 0);
        __builtin_amdgcn_s_setprio(0);
    };
    auto MFMA_G = [&]() {
        __builtin_amdgcn_s_setprio(1);
#pragma unroll
        for (int m = 0; m < 4; ++m)
#pragma unroll
            for (int n = 0; n < 4; ++n)
                acc[m][n] = __builtin_amdgcn_mfma_f32_16x16x32_bf16(
                    ga[m], gb[n], acc[m][n], 0, 0, 0);
        __builtin_amdgcn_s_setprio(0);
    };

    // prologue: issue A(0), B(0), A(1) -> 10 loads; publish tile 0; preload f
    STAGE_A(0, 0); STAGE_B(0, 0); STAGE_A(1, 1);
    asm volatile("s_waitcnt vmcnt(4)" ::: "memory");
    __builtin_amdgcn_s_barrier();
    READ_F(&lds[0], &lds[49152], swz0);

    int a_cur = 0;                           // t % 3
    for (int t = 0; t < NT; ++t) {
        const u16* Ab = &lds[a_cur * 16384];
        const u16* Bb = &lds[49152 + (t & 1) * 8192];

        if (t + 1 < NT) STAGE_B((t + 1) & 1, t + 1);       // 2 gloads/wave
        MFMA_F();                                          // phase 0 (kk=0)
        if (t + 2 < NT) {
            int a_nxt = a_cur - 1; if (a_nxt < 0) a_nxt = 2;   // (t+2) % 3
            STAGE_A(a_nxt, t + 2);                         // 4 gloads/wave
        }
        READ_G(Ab, Bb, swz1);                              // frags for phase 1
        MFMA_G();                                          // phase 1 (kk=1)

        if (t + 1 < NT) {
            // publish tile t+1: my A(t+1),B(t+1) landed; A(t+2) may stay in flight
            if (t + 2 < NT) asm volatile("s_waitcnt vmcnt(4)" ::: "memory");
            else            asm volatile("s_waitcnt vmcnt(0)" ::: "memory");
            __builtin_amdgcn_s_barrier();
            int a_n = a_cur + 1; if (a_n == 3) a_n = 0;
            READ_F(&lds[a_n * 16384], &lds[49152 + ((t + 1) & 1) * 8192], swz0);
        }
        ++a_cur; if (a_cur == 3) a_cur = 0;
    }

    // epilogue: C/D layout col=lane&15, row=(lane>>4)*4+reg  [m89/m91]
    const int crow = (int)row0 + wr * 64 + fq * 4;
    const int ccol = (int)col0 + wc * 64 + fr;
    float dc[4];
    if constexpr (EPI) {
#pragma unroll
        for (int n = 0; n < 4; ++n) dc[n] = D[ccol + n * 16];
    }
#pragma unroll
    for (int m = 0; m < 4; ++m)
#pragma unroll
        for (int n = 0; n < 4; ++n) {
            int cc = ccol + n * 16;
#pragma unroll
            for (int j = 0; j < 4; ++j) {
                int r = crow + m * 16 + j;
                size_t p = (size_t)r * N2 + cc;
                float v = acc[m][n][j];
                if constexpr (EPI) v += dc[n] * bf2f(Ubf[p]);
                C[p] = v;
            }
        }
}

// ---------------------------------------------------------------------------
// Scan, recompute scheme.  Bu layout [T, 2N]: re at col c, im at col c+N.
// pass 1: per-(chunk,chan) local carry only (read Bu once, no Bu writes)
// ---------------------------------------------------------------------------
__global__ __launch_bounds__(256) void carry_pass_k(const float* __restrict__ Bu,
                                                    const float* __restrict__ nu,
                                                    const float* __restrict__ theta,
                                                    float* __restrict__ car) {
    int idx = blockIdx.x * 256 + threadIdx.x;   // 0 .. NCHUNK*N-1
    int chan = idx & (N_DIM - 1);
    int chunk = idx >> 10;
    float a = expf(nu[chan]), b = expf(theta[chan]);
    float m = expf(-a), s, c;
    __sincosf(b, &s, &c);
    float lr = m * c, li = m * s;
    float hr = 0.f, hi = 0.f;
    size_t base = (size_t)chunk * CHUNK * N2 + chan;
    for (int i = 0; i < CHUNK; ++i) {
        size_t p = base + (size_t)i * N2;
        float br = Bu[p], bi = Bu[p + N_DIM];
        float nr = fmaf(lr, hr, fmaf(-li, hi, br));
        float ni = fmaf(lr, hi, fmaf(li, hr, bi));
        hr = nr; hi = ni;
    }
    car[(size_t)chunk * N2 + chan] = hr;
    car[(size_t)chunk * N2 + N_DIM + chan] = hi;
}

// pass 2: combine carries across chunks (per channel, lambda^CHUNK closed form)
__global__ __launch_bounds__(256) void scan_carry_k(float* __restrict__ car,
                                                    const float* __restrict__ nu,
                                                    const float* __restrict__ theta) {
    __shared__ float sR[NCHUNK][65], sI[NCHUNK][65];
    int tid = threadIdx.x;
    int chan0 = blockIdx.x * 64;
    for (int i = tid; i < NCHUNK * 64; i += 256) {
        int ck = i >> 6, c = i & 63;
        sR[ck][c] = car[(size_t)ck * N2 + chan0 + c];
        sI[ck][c] = car[(size_t)ck * N2 + N_DIM + chan0 + c];
    }
    __syncthreads();
    if (tid < 64) {
        int chan = chan0 + tid;
        float a = expf(nu[chan]), b = expf(theta[chan]);
        float m = expf(-(float)CHUNK * a), s, c;
        __sincosf((float)CHUNK * b, &s, &c);
        float lr = m * c, li = m * s;
        float hr = sR[0][tid], hi = sI[0][tid];
        for (int ck = 1; ck < NCHUNK; ++ck) {
            float nr = fmaf(lr, hr, fmaf(-li, hi, sR[ck][tid]));
            float ni = fmaf(lr, hi, fmaf(li, hr, sI[ck][tid]));
            hr = nr; hi = ni;
            sR[ck][tid] = hr; sI[ck][tid] = hi;
        }
    }
    __syncthreads();
    for (int i = tid; i < NCHUNK * 64; i += 256) {
        int ck = i >> 6, c = i & 63;
        car[(size_t)ck * N2 + chan0 + c] = sR[ck][c];
        car[(size_t)ck * N2 + N_DIM + chan0 + c] = sI[ck][c];
    }
}

// pass 3: recompute local scan seeded with combined carry, write bf16 h
__global__ __launch_bounds__(256) void scan_out_k(const float* __restrict__ Bu,
                                                  const float* __restrict__ car,
                                                  const float* __restrict__ nu,
                                                  const float* __restrict__ theta,
                                                  u16* __restrict__ Hbf) {
    int idx = blockIdx.x * 256 + threadIdx.x;   // 0 .. NCHUNK*N-1
    int chan = idx & (N_DIM - 1);
    int chunk = idx >> 10;
    float a = expf(nu[chan]), b = expf(theta[chan]);
    float m = expf(-a), s, c;
    __sincosf(b, &s, &c);
    float lr = m * c, li = m * s;
    float hr = 0.f, hi = 0.f;
    if (chunk > 0) {
        size_t cp = (size_t)(chunk - 1) * N2 + chan;
        hr = car[cp]; hi = car[cp + N_DIM];
    }
    size_t base = (size_t)chunk * CHUNK * N2 + chan;
    for (int i = 0; i < CHUNK; ++i) {
        size_t p = base + (size_t)i * N2;
        float br = Bu[p], bi = Bu[p + N_DIM];
        float nr = fmaf(lr, hr, fmaf(-li, hi, br));
        float ni = fmaf(lr, hi, fmaf(li, hr, bi));
        hr = nr; hi = ni;
        Hbf[p] = f2bf(hr);
        Hbf[p + N_DIM] = f2bf(hi);
    }
}

extern "C" void kernel_launch(void* const* d_in, const int* in_sizes, int n_in,
                              void* d_out, int out_size, void* d_ws, size_t ws_size,
                              hipStream_t stream) {
    const float* U     = (const float*)d_in[0];   // [T,H]
    const float* nu    = (const float*)d_in[1];   // [N]
    const float* theta = (const float*)d_in[2];   // [N]
    const float* glog  = (const float*)d_in[3];   // [N]
    const float* Bre   = (const float*)d_in[4];   // [N,H]
    const float* Bim   = (const float*)d_in[5];   // [N,H]
    const float* Cre   = (const float*)d_in[6];   // [H,N]
    const float* Cim   = (const float*)d_in[7];   // [H,N]
    const float* Dp    = (const float*)d_in[8];   // [H]
    float* Y = (float*)d_out;

    u16* Ubf  = (u16*)d_ws;                             // T*H       bf16
    u16* Bcat = Ubf + (size_t)T_DIM * H_DIM;            // 2N*H      bf16
    u16* Ccat = Bcat + (size_t)N2 * H_DIM;              // H*2N      bf16
    u16* Hbf  = Ccat + (size_t)H_DIM * N2;              // T*2N      bf16
    float* Bu = (float*)(Hbf + (size_t)T_DIM * N2);     // T*2N      f32
    float* car = Bu + (size_t)T_DIM * N2;               // NCHUNK*2N f32

    cvt_u_k<<<(T_DIM * H_DIM / 4) / 256, 256, 0, stream>>>(U, Ubf);
    cvt_b_k<<<((size_t)N2 * H_DIM / 4) / 256, 256, 0, stream>>>(Bre, Bim, glog, Bcat);
    cvt_c_k<<<((size_t)H_DIM * N2 / 4) / 256, 256, 0, stream>>>(Cre, Cim, Ccat);

    gemm_pipe<0><<<256, 512, 0, stream>>>(Ubf, Bcat, Bu, nullptr, nullptr);

    carry_pass_k<<<(NCHUNK * N_DIM) / 256, 256, 0, stream>>>(Bu, nu, theta, car);
    scan_carry_k<<<N_DIM / 64, 256, 0, stream>>>(car, nu, theta);
    scan_out_k<<<(NCHUNK * N_DIM) / 256, 256, 0, stream>>>(Bu, car, nu, theta, Hbf);

    gemm_pipe<1><<<256, 512, 0, stream>>>(Hbf, Ccat, Y, Dp, Ubf);
}